// Round 12
// baseline (494.272 us; speedup 1.0000x reference)
//
#include <hip/hip_runtime.h>

// GCN: 3x GCNConv(sym-norm, self-loops) + ReLU, mean-pool per graph, FC.
// Strategy: fold dinv into per-layer G = dinv .* (X@W); build dst-CSR once
// per call so aggregation is atomic-free.
// R1-R7: chased store-coalescing; falsified. True model: WRITE ~= 32B x
//   (# global no-return atomics) + stores; atomics also latency-bound.
// R8: zero global atomics in CSR build -> 480us.
// R9: chunk-per-XCD G layout FAILED (fills not retained + 8x col). Reverted.
// R10: G fp16 (64B row = 1 line/edge-gather) -> 437us, agg 56us, FETCH
//   124MB = 12.8 col + 51 compulsory (8 XCD x 6.4MB) + ~60 churn (G > 4MB L2).
// R11: src-split two-phase agg. Rows partitioned (src<50K | >=50K) via
//   mid_ptr; phase 0 sums half-A (3.2MB working set, L2-resident/XCD) into
//   raw fp32 partials, phase 1 adds half-B + bias/relu. Kills the churn at
//   the cost of one Xout round-trip.
//   (R11a: nt builtins reject HIP_vector_type — plain load for partials.)

#include <hip/hip_fp16.h>

#define NN 100000
#define NHALF 50000
#define EE 3200000
#define FIN 128
#define HID 32
#define NGR 256
#define NC 10
#define NBUK 256
#define BRANGE 391    // 256*391 = 100096 >= NN
#define BSLACK 13400  // mean 12500, sd ~112 -> ~8 sigma slack (input is fixed)
#define TILE 8192

typedef _Float16 h2 __attribute__((ext_vector_type(2)));
typedef _Float16 h4 __attribute__((ext_vector_type(4)));

__global__ void k_init(int* __restrict__ bcur) {
  int t = threadIdx.x;
  if (t < NBUK) bcur[t] = t * BSLACK;
}

// Pass A: LDS multisplit of one 8192-edge tile into 256 dst-buckets.
__global__ __launch_bounds__(256) void k_bucket(const int* __restrict__ ei,
                                                int* __restrict__ bcur,
                                                long long* __restrict__ bpair) {
  __shared__ int hist[NBUK];
  __shared__ int bexc[NBUK];
  __shared__ int cnt[NBUK];
  __shared__ int gofs[NBUK];
  __shared__ long long sorted[TILE];  // 64 KB
  int t = threadIdx.x;
  const int* src = ei;
  const int* dst = ei + EE;
  int e0 = blockIdx.x * TILE;
  int tn = EE - e0;
  if (tn > TILE) tn = TILE;

  hist[t] = 0;
  cnt[t] = 0;
  __syncthreads();

  for (int i = t; i < tn; i += 256) {
    int d = __builtin_nontemporal_load(&dst[e0 + i]);
    atomicAdd(&hist[d / BRANGE], 1);
  }
  __syncthreads();

  int hv = hist[t];
  bexc[t] = hv;
  __syncthreads();
#pragma unroll
  for (int off = 1; off < NBUK; off <<= 1) {
    int x = (t >= off) ? bexc[t - off] : 0;
    __syncthreads();
    bexc[t] += x;
    __syncthreads();
  }
  {
    int inc = bexc[t];
    bexc[t] = inc - hv;
    if (hv > 0) gofs[t] = atomicAdd(&bcur[t], hv);  // ~65K atomics total
  }
  __syncthreads();

  for (int i = t; i < tn; i += 256) {
    int d = dst[e0 + i];
    int s = src[e0 + i];
    int q = d / BRANGE;
    int p = bexc[q] + atomicAdd(&cnt[q], 1);
    sorted[p] = ((long long)(unsigned)d << 32) | (unsigned)s;
  }
  __syncthreads();

  for (int i = t; i < tn; i += 256) {
    long long pr = sorted[i];
    int q = (int)(unsigned)(pr >> 32) / BRANGE;
    __builtin_nontemporal_store(pr, &bpair[(size_t)gofs[q] + (i - bexc[q])]);
  }
}

// Fused CSR finalize: one block per bucket, zero global atomics.
// R11: rows are 2-way partitioned by src-half; mid_ptr marks the split.
__global__ __launch_bounds__(256) void k_place(const long long* __restrict__ bpair,
                                               const int* __restrict__ bcur,
                                               float* __restrict__ dinv,
                                               int* __restrict__ row_ptr,
                                               int* __restrict__ mid_ptr,
                                               int* __restrict__ col) {
  __shared__ int bs[NBUK];
  __shared__ int cntA[BRANGE];  // half-A counts -> cursors
  __shared__ int cntB[BRANGE];  // half-B counts -> cursors
  __shared__ int thsum[256];
  int b = blockIdx.x, t = threadIdx.x;

  bs[t] = bcur[t] - t * BSLACK;
  __syncthreads();
#pragma unroll
  for (int off = 1; off < NBUK; off <<= 1) {
    int x = (t >= off) ? bs[t - off] : 0;
    __syncthreads();
    bs[t] += x;
    __syncthreads();
  }
  int sz = bcur[b] - b * BSLACK;
  int colbase = bs[b] - sz;

  for (int i = t; i < BRANGE; i += 256) { cntA[i] = 0; cntB[i] = 0; }
  __syncthreads();

  int lo = b * BRANGE;
  int nnode = NN - lo;
  if (nnode > BRANGE) nnode = BRANGE;
  size_t e0 = (size_t)b * BSLACK;

  for (int i = t; i < sz; i += 256) {
    long long pr = bpair[e0 + i];
    int d = (int)(unsigned)(pr >> 32);
    int s = (int)(unsigned)(pr & 0xffffffffLL);
    atomicAdd(s < NHALF ? &cntA[d - lo] : &cntB[d - lo], 1);
  }
  __syncthreads();

  int i0 = 2 * t, i1 = 2 * t + 1;
  int a0 = (i0 < BRANGE) ? cntA[i0] : 0;
  int b0 = (i0 < BRANGE) ? cntB[i0] : 0;
  int a1 = (i1 < BRANGE) ? cntA[i1] : 0;
  int b1 = (i1 < BRANGE) ? cntB[i1] : 0;
  int tot0 = a0 + b0, tot1 = a1 + b1;
  thsum[t] = tot0 + tot1;
  __syncthreads();
#pragma unroll
  for (int off = 1; off < 256; off <<= 1) {
    int x = (t >= off) ? thsum[t - off] : 0;
    __syncthreads();
    thsum[t] += x;
    __syncthreads();
  }
  int run = thsum[t] - (tot0 + tot1);
  if (i0 < nnode) {
    row_ptr[lo + i0] = colbase + run;
    mid_ptr[lo + i0] = colbase + run + a0;
    dinv[lo + i0] = rsqrtf((float)(tot0 + 1));  // +1 = self-loop
  }
  if (i0 < BRANGE) { cntA[i0] = colbase + run; cntB[i0] = colbase + run + a0; }
  run += tot0;
  if (i1 < nnode) {
    row_ptr[lo + i1] = colbase + run;
    mid_ptr[lo + i1] = colbase + run + a1;
    dinv[lo + i1] = rsqrtf((float)(tot1 + 1));
  }
  if (i1 < BRANGE) { cntA[i1] = colbase + run; cntB[i1] = colbase + run + a1; }
  if (b == NBUK - 1 && t == 0) row_ptr[NN] = EE;
  __syncthreads();

  for (int i = t; i < sz; i += 256) {
    long long pr = bpair[e0 + i];
    int d = (int)(unsigned)(pr >> 32);
    int s = (int)(unsigned)(pr & 0xffffffffLL);
    int pos = atomicAdd(s < NHALF ? &cntA[d - lo] : &cntB[d - lo], 1);
    col[pos] = s;
  }
}

// G = dinv .* (X @ W), stored fp16 [node][32] (64B rows = 1 cache line).
template <int K>
__global__ __launch_bounds__(256) void k_gemm(const float* __restrict__ X,
                                              const float* __restrict__ W,
                                              const float* __restrict__ dinv,
                                              _Float16* __restrict__ Gout) {
  __shared__ float Wl[K * HID];
  __shared__ float xs[128 * 36];
  int t = threadIdx.x;
  for (int i = t; i < K * HID; i += 256) Wl[i] = W[i];
  int node0 = blockIdx.x * 128;
  int ng = t >> 3, f4 = t & 7;
  float acc[4][4];
#pragma unroll
  for (int j = 0; j < 4; j++)
#pragma unroll
    for (int c = 0; c < 4; c++) acc[j][c] = 0.f;

  for (int kc = 0; kc < K; kc += 32) {
    __syncthreads();
#pragma unroll
    for (int j = 0; j < 4; j++) {
      int idx = t + 256 * j;
      int r = idx >> 3, c4 = idx & 7;
      int row = node0 + r;
      if (row >= NN) row = NN - 1;
      float4 v = *reinterpret_cast<const float4*>(&X[(size_t)row * K + kc + c4 * 4]);
      *reinterpret_cast<float4*>(&xs[r * 36 + c4 * 4]) = v;
    }
    __syncthreads();
#pragma unroll
    for (int k4 = 0; k4 < 8; k4++) {
      float4 xv[4];
#pragma unroll
      for (int j = 0; j < 4; j++)
        xv[j] = *reinterpret_cast<const float4*>(&xs[(ng * 4 + j) * 36 + k4 * 4]);
#pragma unroll
      for (int kk = 0; kk < 4; kk++) {
        float4 wv = *reinterpret_cast<const float4*>(&Wl[(kc + k4 * 4 + kk) * HID + f4 * 4]);
#pragma unroll
        for (int j = 0; j < 4; j++) {
          float xvj = (kk == 0) ? xv[j].x : (kk == 1) ? xv[j].y : (kk == 2) ? xv[j].z : xv[j].w;
          acc[j][0] += xvj * wv.x;
          acc[j][1] += xvj * wv.y;
          acc[j][2] += xvj * wv.z;
          acc[j][3] += xvj * wv.w;
        }
      }
    }
  }
#pragma unroll
  for (int j = 0; j < 4; j++) {
    int node = node0 + ng * 4 + j;
    if (node < NN) {
      float s = dinv[node];
      h4 o;
      o.x = (_Float16)(acc[j][0] * s);
      o.y = (_Float16)(acc[j][1] * s);
      o.z = (_Float16)(acc[j][2] * s);
      o.w = (_Float16)(acc[j][3] * s);
      reinterpret_cast<h4*>(Gout)[(size_t)node * 8 + f4] = o;
    }
  }
}

// Two-phase agg. Phase 0: raw sums over src<NHALF segment (+self if n<NHALF)
// -> Xout (fp32 partials). Phase 1: += src>=NHALF segment (+self if
// n>=NHALF), then dinv/bias/relu. Working set per phase = 3.2MB G-half,
// L2-resident per XCD. 16 lanes x h2/node; 8-deep gather ILP.
__global__ __launch_bounds__(256) void k_agg(const _Float16* __restrict__ Gin,
                                             const int* __restrict__ col,
                                             const int* __restrict__ row_ptr,
                                             const int* __restrict__ mid_ptr,
                                             const float* __restrict__ dinv,
                                             const float* __restrict__ bias,
                                             float* __restrict__ Xout,
                                             int relu, int phase) {
  const h2* G2 = reinterpret_cast<const h2*>(Gin);
  int t = threadIdx.x;
  int h = t & 15;          // h2 index within row (feats 2h, 2h+1)
  int slot = t >> 4;       // 0..15 node slot within block
  int n = blockIdx.x * 16 + slot;
  int beg, end;
  float ax0, ay0;
  if (phase == 0) {
    beg = row_ptr[n];
    end = mid_ptr[n];
    ax0 = 0.f; ay0 = 0.f;
    if (n < NHALF) {
      h2 g0 = G2[(size_t)n * 16 + h];
      ax0 = (float)g0.x; ay0 = (float)g0.y;
    }
  } else {
    beg = mid_ptr[n];
    end = row_ptr[n + 1];
    float2 p = reinterpret_cast<const float2*>(Xout)[(size_t)n * 16 + h];
    ax0 = p.x; ay0 = p.y;
    if (n >= NHALF) {
      h2 g0 = G2[(size_t)n * 16 + h];
      ax0 += (float)g0.x; ay0 += (float)g0.y;
    }
  }
  float ax1 = 0.f, ay1 = 0.f, ax2 = 0.f, ay2 = 0.f, ax3 = 0.f, ay3 = 0.f;
  float ax4 = 0.f, ay4 = 0.f, ax5 = 0.f, ay5 = 0.f, ax6 = 0.f, ay6 = 0.f;
  float ax7 = 0.f, ay7 = 0.f;

  int i = beg;
  for (; i + 8 <= end; i += 8) {
    int s0 = __builtin_nontemporal_load(&col[i + 0]);
    int s1 = __builtin_nontemporal_load(&col[i + 1]);
    int s2 = __builtin_nontemporal_load(&col[i + 2]);
    int s3 = __builtin_nontemporal_load(&col[i + 3]);
    int s4 = __builtin_nontemporal_load(&col[i + 4]);
    int s5 = __builtin_nontemporal_load(&col[i + 5]);
    int s6 = __builtin_nontemporal_load(&col[i + 6]);
    int s7 = __builtin_nontemporal_load(&col[i + 7]);
    h2 v0 = G2[(size_t)s0 * 16 + h];
    h2 v1 = G2[(size_t)s1 * 16 + h];
    h2 v2 = G2[(size_t)s2 * 16 + h];
    h2 v3 = G2[(size_t)s3 * 16 + h];
    h2 v4 = G2[(size_t)s4 * 16 + h];
    h2 v5 = G2[(size_t)s5 * 16 + h];
    h2 v6 = G2[(size_t)s6 * 16 + h];
    h2 v7 = G2[(size_t)s7 * 16 + h];
    ax0 += (float)v0.x; ay0 += (float)v0.y;
    ax1 += (float)v1.x; ay1 += (float)v1.y;
    ax2 += (float)v2.x; ay2 += (float)v2.y;
    ax3 += (float)v3.x; ay3 += (float)v3.y;
    ax4 += (float)v4.x; ay4 += (float)v4.y;
    ax5 += (float)v5.x; ay5 += (float)v5.y;
    ax6 += (float)v6.x; ay6 += (float)v6.y;
    ax7 += (float)v7.x; ay7 += (float)v7.y;
  }
  for (; i < end; i++) {
    int s = __builtin_nontemporal_load(&col[i]);
    h2 v = G2[(size_t)s * 16 + h];
    ax0 += (float)v.x; ay0 += (float)v.y;
  }
  ax0 += ax1 + ax2 + ax3 + ax4 + ax5 + ax6 + ax7;
  ay0 += ay1 + ay2 + ay3 + ay4 + ay5 + ay6 + ay7;

  float2 v;
  if (phase == 0) {
    v.x = ax0;
    v.y = ay0;
  } else {
    float s = dinv[n];
    float2 b = reinterpret_cast<const float2*>(bias)[h];
    v.x = s * ax0 + b.x;
    v.y = s * ay0 + b.y;
    if (relu) {
      v.x = fmaxf(v.x, 0.f);
      v.y = fmaxf(v.y, 0.f);
    }
  }
  reinterpret_cast<float2*>(Xout)[(size_t)n * 16 + h] = v;
}

// Mean-pool: batch is sorted, so flush-on-graph-change keeps atomics rare.
__global__ __launch_bounds__(256) void k_pool(const float* __restrict__ X,
                                              const int* __restrict__ batch,
                                              float* __restrict__ sums,
                                              int* __restrict__ counts) {
  int t = threadIdx.x;
  int f = t & 31, slot = t >> 5;
  int base = blockIdx.x * 512;
  float acc = 0.f;
  int cnt = 0, cur = -1;
  for (int i = 0; i < 64; i++) {
    int n = base + slot + i * 8;
    if (n >= NN) break;
    int g = batch[n];
    if (g != cur) {
      if (cur >= 0) {
        atomicAdd(&sums[cur * HID + f], acc);
        if (f == 0) atomicAdd(&counts[cur], cnt);
      }
      cur = g;
      acc = 0.f;
      cnt = 0;
    }
    acc += X[(size_t)n * HID + f];
    cnt++;
  }
  if (cur >= 0) {
    atomicAdd(&sums[cur * HID + f], acc);
    if (f == 0) atomicAdd(&counts[cur], cnt);
  }
}

__global__ void k_fc(const float* __restrict__ sums, const int* __restrict__ counts,
                     const float* __restrict__ Wfc, const float* __restrict__ bfc,
                     float* __restrict__ out) {
  int idx = blockIdx.x * 256 + threadIdx.x;
  if (idx >= NGR * NC) return;
  int g = idx / NC, c = idx % NC;
  float inv = 1.f / fmaxf((float)counts[g], 1.f);
  float acc = bfc[c];
#pragma unroll
  for (int k = 0; k < HID; k++) acc += sums[g * HID + k] * inv * Wfc[k * NC + c];
  out[idx] = acc;
}

extern "C" void kernel_launch(void* const* d_in, const int* in_sizes, int n_in,
                              void* d_out, int out_size, void* d_ws, size_t ws_size,
                              hipStream_t stream) {
  (void)in_sizes; (void)n_in; (void)out_size; (void)ws_size;
  const float* x = (const float*)d_in[0];
  const int* ei = (const int*)d_in[1];
  const int* batch = (const int*)d_in[2];
  const float* W1 = (const float*)d_in[3];
  const float* b1 = (const float*)d_in[4];
  const float* W2 = (const float*)d_in[5];
  const float* b2 = (const float*)d_in[6];
  const float* W3 = (const float*)d_in[7];
  const float* b3 = (const float*)d_in[8];
  const float* Wfc = (const float*)d_in[9];
  const float* bfc = (const float*)d_in[10];
  float* out = (float*)d_out;

  char* ws = (char*)d_ws;
  size_t off = 0;
  auto alloc = [&](size_t bytes) -> void* {
    void* p = ws + off;
    off = (off + bytes + 255) & ~(size_t)255;
    return p;
  };
  float* dinv = (float*)alloc((size_t)NN * 4);
  int* row_ptr = (int*)alloc((size_t)(NN + 1) * 4);
  int* mid_ptr = (int*)alloc((size_t)NN * 4);
  int* bcur = (int*)alloc(NBUK * 4);
  int* col = (int*)alloc((size_t)EE * 4);
  // Union region: bpair (CSR build only) overlaps Gbuf+Abuf (GEMM phase only).
  size_t bpair_bytes = (size_t)NBUK * BSLACK * 8;          // 27.4 MB
  size_t gbuf_bytes = (size_t)NN * HID * 2;                // 6.4 MB (fp16)
  size_t abuf_bytes = (size_t)NN * HID * 4;                // 12.8 MB (fp32)
  size_t need = gbuf_bytes + abuf_bytes;
  char* uni = (char*)alloc(bpair_bytes > need ? bpair_bytes : need);
  long long* bpair = (long long*)uni;
  _Float16* Gbuf = (_Float16*)uni;
  float* Abuf = (float*)(uni + gbuf_bytes);
  float* sums = (float*)alloc((size_t)NGR * HID * 4);
  int* counts = (int*)alloc((size_t)NGR * 4);

  hipMemsetAsync(sums, 0, (size_t)NGR * HID * 4, stream);
  hipMemsetAsync(counts, 0, (size_t)NGR * 4, stream);

  k_init<<<1, NBUK, 0, stream>>>(bcur);
  k_bucket<<<(EE + TILE - 1) / TILE, 256, 0, stream>>>(ei, bcur, bpair);
  k_place<<<NBUK, 256, 0, stream>>>(bpair, bcur, dinv, row_ptr, mid_ptr, col);

  k_gemm<FIN><<<(NN + 127) / 128, 256, 0, stream>>>(x, W1, dinv, Gbuf);
  k_agg<<<NN / 16, 256, 0, stream>>>(Gbuf, col, row_ptr, mid_ptr, dinv, b1, Abuf, 1, 0);
  k_agg<<<NN / 16, 256, 0, stream>>>(Gbuf, col, row_ptr, mid_ptr, dinv, b1, Abuf, 1, 1);
  k_gemm<HID><<<(NN + 127) / 128, 256, 0, stream>>>(Abuf, W2, dinv, Gbuf);
  k_agg<<<NN / 16, 256, 0, stream>>>(Gbuf, col, row_ptr, mid_ptr, dinv, b2, Abuf, 1, 0);
  k_agg<<<NN / 16, 256, 0, stream>>>(Gbuf, col, row_ptr, mid_ptr, dinv, b2, Abuf, 1, 1);
  k_gemm<HID><<<(NN + 127) / 128, 256, 0, stream>>>(Abuf, W3, dinv, Gbuf);
  k_agg<<<NN / 16, 256, 0, stream>>>(Gbuf, col, row_ptr, mid_ptr, dinv, b3, Abuf, 0, 0);
  k_agg<<<NN / 16, 256, 0, stream>>>(Gbuf, col, row_ptr, mid_ptr, dinv, b3, Abuf, 0, 1);

  k_pool<<<(NN + 511) / 512, 256, 0, stream>>>(Abuf, batch, sums, counts);
  k_fc<<<(NGR * NC + 255) / 256, 256, 0, stream>>>(sums, counts, Wfc, bfc, out);
}

// Round 13
// 405.234 us; speedup vs baseline: 1.2197x; 1.2197x over previous
//
#include <hip/hip_runtime.h>

// GCN: 3x GCNConv(sym-norm, self-loops) + ReLU, mean-pool per graph, FC.
// Strategy: fold dinv into per-layer G = dinv .* (X@W); build dst-CSR once
// per call so aggregation is atomic-free.
// R1-R7: chased store-coalescing; falsified. True model: WRITE ~= 32B x
//   (# global no-return atomics) + stores; atomics also latency-bound.
// R8: zero global atomics in CSR build -> 480us.
// R9: chunk-per-XCD G layout FAILED. R11/R12: src-split two-phase agg FAILED
//   (437->494): Xout round-trip outweighed churn savings. Third failed L2-
//   residency bet -- multi-XCD random gathers defeat retention games. Accept
//   gather misses; optimize wave-level latency hiding instead.
// R10 (kept): G fp16, 64B row = 1 line/edge-gather; agg 56us x3.
// R13: revert to R10 agg; k_bucket/k_place widened to 1024-thread blocks.
//   k_place was 49us at 9% occupancy (1 wave/SIMD, pure latency). 4x waves
//   -> predict ~15-18us; k_bucket similarly ~20us.

#include <hip/hip_fp16.h>

#define NN 100000
#define EE 3200000
#define FIN 128
#define HID 32
#define NGR 256
#define NC 10
#define NBUK 256
#define BRANGE 391    // 256*391 = 100096 >= NN
#define BSLACK 13400  // mean 12500, sd ~112 -> ~8 sigma slack (input is fixed)
#define TILE 8192

typedef _Float16 h2 __attribute__((ext_vector_type(2)));
typedef _Float16 h4 __attribute__((ext_vector_type(4)));

__global__ void k_init(int* __restrict__ bcur) {
  int t = threadIdx.x;
  if (t < NBUK) bcur[t] = t * BSLACK;
}

// Pass A: LDS multisplit of one 8192-edge tile into 256 dst-buckets.
// 1024 threads/block for latency hiding (R13).
__global__ __launch_bounds__(1024) void k_bucket(const int* __restrict__ ei,
                                                 int* __restrict__ bcur,
                                                 long long* __restrict__ bpair) {
  __shared__ int hist[NBUK];
  __shared__ int bexc[NBUK];
  __shared__ int cnt[NBUK];
  __shared__ int gofs[NBUK];
  __shared__ long long sorted[TILE];  // 64 KB
  int t = threadIdx.x;
  const int* src = ei;
  const int* dst = ei + EE;
  int e0 = blockIdx.x * TILE;
  int tn = EE - e0;
  if (tn > TILE) tn = TILE;

  if (t < NBUK) { hist[t] = 0; cnt[t] = 0; }
  __syncthreads();

  for (int i = t; i < tn; i += 1024) {
    int d = __builtin_nontemporal_load(&dst[e0 + i]);
    atomicAdd(&hist[d / BRANGE], 1);
  }
  __syncthreads();

  int hv = 0;
  if (t < NBUK) { hv = hist[t]; bexc[t] = hv; }
  __syncthreads();
#pragma unroll
  for (int off = 1; off < NBUK; off <<= 1) {
    int x = 0;
    if (t < NBUK && t >= off) x = bexc[t - off];
    __syncthreads();
    if (t < NBUK) bexc[t] += x;
    __syncthreads();
  }
  if (t < NBUK) {
    int inc = bexc[t];
    bexc[t] = inc - hv;
    if (hv > 0) gofs[t] = atomicAdd(&bcur[t], hv);  // ~65K atomics total
  }
  __syncthreads();

  for (int i = t; i < tn; i += 1024) {
    int d = dst[e0 + i];
    int s = src[e0 + i];
    int q = d / BRANGE;
    int p = bexc[q] + atomicAdd(&cnt[q], 1);
    sorted[p] = ((long long)(unsigned)d << 32) | (unsigned)s;
  }
  __syncthreads();

  for (int i = t; i < tn; i += 1024) {
    long long pr = sorted[i];
    int q = (int)(unsigned)(pr >> 32) / BRANGE;
    __builtin_nontemporal_store(pr, &bpair[(size_t)gofs[q] + (i - bexc[q])]);
  }
}

// Fused CSR finalize: one 1024-thread block per bucket, zero global atomics.
__global__ __launch_bounds__(1024) void k_place(const long long* __restrict__ bpair,
                                                const int* __restrict__ bcur,
                                                float* __restrict__ dinv,
                                                int* __restrict__ row_ptr,
                                                int* __restrict__ col) {
  __shared__ int bs[NBUK];
  __shared__ int cnt[BRANGE];
  __shared__ int sc[1024];
  int b = blockIdx.x, t = threadIdx.x;

  if (t < NBUK) bs[t] = bcur[t] - t * BSLACK;
  __syncthreads();
#pragma unroll
  for (int off = 1; off < NBUK; off <<= 1) {
    int x = 0;
    if (t < NBUK && t >= off) x = bs[t - off];
    __syncthreads();
    if (t < NBUK) bs[t] += x;
    __syncthreads();
  }
  __syncthreads();
  int sz = bcur[b] - b * BSLACK;
  int colbase = bs[b] - sz;

  if (t < BRANGE) cnt[t] = 0;
  __syncthreads();

  int lo = b * BRANGE;
  int nnode = NN - lo;
  if (nnode > BRANGE) nnode = BRANGE;
  size_t e0 = (size_t)b * BSLACK;

  // Histogram dst within bucket (LDS atomics).
  for (int i = t; i < sz; i += 1024) {
    long long pr = bpair[e0 + i];
    int d = (int)(unsigned)(pr >> 32);
    atomicAdd(&cnt[d - lo], 1);
  }
  __syncthreads();

  // Exclusive scan of cnt[0..BRANGE) via 1024-wide Hillis-Steele.
  int v = (t < BRANGE) ? cnt[t] : 0;
  sc[t] = v;
  __syncthreads();
#pragma unroll
  for (int off = 1; off < 1024; off <<= 1) {
    int x = (t >= off) ? sc[t - off] : 0;
    __syncthreads();
    sc[t] += x;
    __syncthreads();
  }
  int excl = sc[t] - v;
  if (t < nnode) {
    row_ptr[lo + t] = colbase + excl;
    dinv[lo + t] = rsqrtf((float)(v + 1));  // +1 = self-loop
  }
  if (t < BRANGE) cnt[t] = colbase + excl;  // absolute cursor
  if (b == NBUK - 1 && t == 0) row_ptr[NN] = EE;
  __syncthreads();

  // Place: LDS cursor atomics, global writes within this block's window.
  for (int i = t; i < sz; i += 1024) {
    long long pr = bpair[e0 + i];
    int d = (int)(unsigned)(pr >> 32);
    int s = (int)(unsigned)(pr & 0xffffffffLL);
    int pos = atomicAdd(&cnt[d - lo], 1);
    col[pos] = s;
  }
}

// G = dinv .* (X @ W), stored fp16 [node][32] (64B rows = 1 cache line).
template <int K>
__global__ __launch_bounds__(256) void k_gemm(const float* __restrict__ X,
                                              const float* __restrict__ W,
                                              const float* __restrict__ dinv,
                                              _Float16* __restrict__ Gout) {
  __shared__ float Wl[K * HID];
  __shared__ float xs[128 * 36];
  int t = threadIdx.x;
  for (int i = t; i < K * HID; i += 256) Wl[i] = W[i];
  int node0 = blockIdx.x * 128;
  int ng = t >> 3, f4 = t & 7;
  float acc[4][4];
#pragma unroll
  for (int j = 0; j < 4; j++)
#pragma unroll
    for (int c = 0; c < 4; c++) acc[j][c] = 0.f;

  for (int kc = 0; kc < K; kc += 32) {
    __syncthreads();
#pragma unroll
    for (int j = 0; j < 4; j++) {
      int idx = t + 256 * j;
      int r = idx >> 3, c4 = idx & 7;
      int row = node0 + r;
      if (row >= NN) row = NN - 1;
      float4 v = *reinterpret_cast<const float4*>(&X[(size_t)row * K + kc + c4 * 4]);
      *reinterpret_cast<float4*>(&xs[r * 36 + c4 * 4]) = v;
    }
    __syncthreads();
#pragma unroll
    for (int k4 = 0; k4 < 8; k4++) {
      float4 xv[4];
#pragma unroll
      for (int j = 0; j < 4; j++)
        xv[j] = *reinterpret_cast<const float4*>(&xs[(ng * 4 + j) * 36 + k4 * 4]);
#pragma unroll
      for (int kk = 0; kk < 4; kk++) {
        float4 wv = *reinterpret_cast<const float4*>(&Wl[(kc + k4 * 4 + kk) * HID + f4 * 4]);
#pragma unroll
        for (int j = 0; j < 4; j++) {
          float xvj = (kk == 0) ? xv[j].x : (kk == 1) ? xv[j].y : (kk == 2) ? xv[j].z : xv[j].w;
          acc[j][0] += xvj * wv.x;
          acc[j][1] += xvj * wv.y;
          acc[j][2] += xvj * wv.z;
          acc[j][3] += xvj * wv.w;
        }
      }
    }
  }
#pragma unroll
  for (int j = 0; j < 4; j++) {
    int node = node0 + ng * 4 + j;
    if (node < NN) {
      float s = dinv[node];
      h4 o;
      o.x = (_Float16)(acc[j][0] * s);
      o.y = (_Float16)(acc[j][1] * s);
      o.z = (_Float16)(acc[j][2] * s);
      o.w = (_Float16)(acc[j][3] * s);
      reinterpret_cast<h4*>(Gout)[(size_t)node * 8 + f4] = o;
    }
  }
}

// X'[n] = act(dinv[n] * (sum G[src] + G[n]) + b). G fp16: 16 lanes x h2
// (4B/lane, 64B/row = one line per edge gather). 16 nodes/block; 8x unroll
// into 8 independent accumulators for 8 outstanding gathers per slot.
__global__ __launch_bounds__(256) void k_agg(const _Float16* __restrict__ Gin,
                                             const int* __restrict__ col,
                                             const int* __restrict__ row_ptr,
                                             const float* __restrict__ dinv,
                                             const float* __restrict__ bias,
                                             float* __restrict__ Xout, int relu) {
  const h2* G2 = reinterpret_cast<const h2*>(Gin);
  int t = threadIdx.x;
  int h = t & 15;          // h2 index within row (feats 2h, 2h+1)
  int slot = t >> 4;       // 0..15 node slot within block
  int n = blockIdx.x * 16 + slot;
  int beg = row_ptr[n], end = row_ptr[n + 1];

  h2 g0 = G2[(size_t)n * 16 + h];  // self-loop term
  float ax0 = (float)g0.x, ay0 = (float)g0.y;
  float ax1 = 0.f, ay1 = 0.f, ax2 = 0.f, ay2 = 0.f, ax3 = 0.f, ay3 = 0.f;
  float ax4 = 0.f, ay4 = 0.f, ax5 = 0.f, ay5 = 0.f, ax6 = 0.f, ay6 = 0.f;
  float ax7 = 0.f, ay7 = 0.f;

  int i = beg;
  for (; i + 8 <= end; i += 8) {
    int s0 = __builtin_nontemporal_load(&col[i + 0]);
    int s1 = __builtin_nontemporal_load(&col[i + 1]);
    int s2 = __builtin_nontemporal_load(&col[i + 2]);
    int s3 = __builtin_nontemporal_load(&col[i + 3]);
    int s4 = __builtin_nontemporal_load(&col[i + 4]);
    int s5 = __builtin_nontemporal_load(&col[i + 5]);
    int s6 = __builtin_nontemporal_load(&col[i + 6]);
    int s7 = __builtin_nontemporal_load(&col[i + 7]);
    h2 v0 = G2[(size_t)s0 * 16 + h];
    h2 v1 = G2[(size_t)s1 * 16 + h];
    h2 v2 = G2[(size_t)s2 * 16 + h];
    h2 v3 = G2[(size_t)s3 * 16 + h];
    h2 v4 = G2[(size_t)s4 * 16 + h];
    h2 v5 = G2[(size_t)s5 * 16 + h];
    h2 v6 = G2[(size_t)s6 * 16 + h];
    h2 v7 = G2[(size_t)s7 * 16 + h];
    ax0 += (float)v0.x; ay0 += (float)v0.y;
    ax1 += (float)v1.x; ay1 += (float)v1.y;
    ax2 += (float)v2.x; ay2 += (float)v2.y;
    ax3 += (float)v3.x; ay3 += (float)v3.y;
    ax4 += (float)v4.x; ay4 += (float)v4.y;
    ax5 += (float)v5.x; ay5 += (float)v5.y;
    ax6 += (float)v6.x; ay6 += (float)v6.y;
    ax7 += (float)v7.x; ay7 += (float)v7.y;
  }
  for (; i < end; i++) {
    int s = __builtin_nontemporal_load(&col[i]);
    h2 v = G2[(size_t)s * 16 + h];
    ax0 += (float)v.x; ay0 += (float)v.y;
  }
  ax0 += ax1 + ax2 + ax3 + ax4 + ax5 + ax6 + ax7;
  ay0 += ay1 + ay2 + ay3 + ay4 + ay5 + ay6 + ay7;

  float s = dinv[n];
  float2 b = reinterpret_cast<const float2*>(bias)[h];
  float2 v;
  v.x = s * ax0 + b.x;
  v.y = s * ay0 + b.y;
  if (relu) {
    v.x = fmaxf(v.x, 0.f);
    v.y = fmaxf(v.y, 0.f);
  }
  reinterpret_cast<float2*>(Xout)[(size_t)n * 16 + h] = v;
}

// Mean-pool: batch is sorted, so flush-on-graph-change keeps atomics rare.
__global__ __launch_bounds__(256) void k_pool(const float* __restrict__ X,
                                              const int* __restrict__ batch,
                                              float* __restrict__ sums,
                                              int* __restrict__ counts) {
  int t = threadIdx.x;
  int f = t & 31, slot = t >> 5;
  int base = blockIdx.x * 512;
  float acc = 0.f;
  int cnt = 0, cur = -1;
  for (int i = 0; i < 64; i++) {
    int n = base + slot + i * 8;
    if (n >= NN) break;
    int g = batch[n];
    if (g != cur) {
      if (cur >= 0) {
        atomicAdd(&sums[cur * HID + f], acc);
        if (f == 0) atomicAdd(&counts[cur], cnt);
      }
      cur = g;
      acc = 0.f;
      cnt = 0;
    }
    acc += X[(size_t)n * HID + f];
    cnt++;
  }
  if (cur >= 0) {
    atomicAdd(&sums[cur * HID + f], acc);
    if (f == 0) atomicAdd(&counts[cur], cnt);
  }
}

__global__ void k_fc(const float* __restrict__ sums, const int* __restrict__ counts,
                     const float* __restrict__ Wfc, const float* __restrict__ bfc,
                     float* __restrict__ out) {
  int idx = blockIdx.x * 256 + threadIdx.x;
  if (idx >= NGR * NC) return;
  int g = idx / NC, c = idx % NC;
  float inv = 1.f / fmaxf((float)counts[g], 1.f);
  float acc = bfc[c];
#pragma unroll
  for (int k = 0; k < HID; k++) acc += sums[g * HID + k] * inv * Wfc[k * NC + c];
  out[idx] = acc;
}

extern "C" void kernel_launch(void* const* d_in, const int* in_sizes, int n_in,
                              void* d_out, int out_size, void* d_ws, size_t ws_size,
                              hipStream_t stream) {
  (void)in_sizes; (void)n_in; (void)out_size; (void)ws_size;
  const float* x = (const float*)d_in[0];
  const int* ei = (const int*)d_in[1];
  const int* batch = (const int*)d_in[2];
  const float* W1 = (const float*)d_in[3];
  const float* b1 = (const float*)d_in[4];
  const float* W2 = (const float*)d_in[5];
  const float* b2 = (const float*)d_in[6];
  const float* W3 = (const float*)d_in[7];
  const float* b3 = (const float*)d_in[8];
  const float* Wfc = (const float*)d_in[9];
  const float* bfc = (const float*)d_in[10];
  float* out = (float*)d_out;

  char* ws = (char*)d_ws;
  size_t off = 0;
  auto alloc = [&](size_t bytes) -> void* {
    void* p = ws + off;
    off = (off + bytes + 255) & ~(size_t)255;
    return p;
  };
  float* dinv = (float*)alloc((size_t)NN * 4);
  int* row_ptr = (int*)alloc((size_t)(NN + 1) * 4);
  int* bcur = (int*)alloc(NBUK * 4);
  int* col = (int*)alloc((size_t)EE * 4);
  // Union region: bpair (CSR build only) overlaps Gbuf+Abuf (GEMM phase only).
  size_t bpair_bytes = (size_t)NBUK * BSLACK * 8;          // 27.4 MB
  size_t gbuf_bytes = (size_t)NN * HID * 2;                // 6.4 MB (fp16)
  size_t abuf_bytes = (size_t)NN * HID * 4;                // 12.8 MB (fp32)
  size_t need = gbuf_bytes + abuf_bytes;
  char* uni = (char*)alloc(bpair_bytes > need ? bpair_bytes : need);
  long long* bpair = (long long*)uni;
  _Float16* Gbuf = (_Float16*)uni;
  float* Abuf = (float*)(uni + gbuf_bytes);
  float* sums = (float*)alloc((size_t)NGR * HID * 4);
  int* counts = (int*)alloc((size_t)NGR * 4);

  hipMemsetAsync(sums, 0, (size_t)NGR * HID * 4, stream);
  hipMemsetAsync(counts, 0, (size_t)NGR * 4, stream);

  k_init<<<1, NBUK, 0, stream>>>(bcur);
  k_bucket<<<(EE + TILE - 1) / TILE, 1024, 0, stream>>>(ei, bcur, bpair);
  k_place<<<NBUK, 1024, 0, stream>>>(bpair, bcur, dinv, row_ptr, col);

  k_gemm<FIN><<<(NN + 127) / 128, 256, 0, stream>>>(x, W1, dinv, Gbuf);
  k_agg<<<NN / 16, 256, 0, stream>>>(Gbuf, col, row_ptr, dinv, b1, Abuf, 1);
  k_gemm<HID><<<(NN + 127) / 128, 256, 0, stream>>>(Abuf, W2, dinv, Gbuf);
  k_agg<<<NN / 16, 256, 0, stream>>>(Gbuf, col, row_ptr, dinv, b2, Abuf, 1);
  k_gemm<HID><<<(NN + 127) / 128, 256, 0, stream>>>(Abuf, W3, dinv, Gbuf);
  k_agg<<<NN / 16, 256, 0, stream>>>(Gbuf, col, row_ptr, dinv, b3, Abuf, 0);

  k_pool<<<(NN + 511) / 512, 256, 0, stream>>>(Abuf, batch, sums, counts);
  k_fc<<<(NGR * NC + 255) / 256, 256, 0, stream>>>(sums, counts, Wfc, bfc, out);
}

// Round 14
// 382.887 us; speedup vs baseline: 1.2909x; 1.0584x over previous
//
#include <hip/hip_runtime.h>

// GCN: 3x GCNConv(sym-norm, self-loops) + ReLU, mean-pool per graph, FC.
// Strategy: fold dinv into per-layer G = dinv .* (X@W); build dst-CSR once
// per call so aggregation is atomic-free.
// R1-R7: store-coalescing chase falsified. True model: WRITE ~= 32B x
//   (# global no-return atomics) + stores; atomics also latency-bound.
// R8: zero global atomics in CSR build. R9/R11/R12: three L2-residency bets
//   failed -- multi-XCD random gathers defeat retention; 124MB FETCH is the
//   gather floor. R10: G fp16 (1 line/edge). R13: 1024-wide bucket/place
//   (occupancy was the whole story) -> 405us; top-5 = 3x k_agg 54us.
// R14: fuse next-layer GEMM (32x32 W, 4KB LDS) into agg epilogue for layers
//   1-2: A[n] is block-complete -> LDS round-trip -> G' fp16 written direct.
//   Deletes 2x k_gemm<32> + 2x Abuf round-trip (25MB/layer), WRITE halves.

#include <hip/hip_fp16.h>

#define NN 100000
#define EE 3200000
#define FIN 128
#define HID 32
#define NGR 256
#define NC 10
#define NBUK 256
#define BRANGE 391    // 256*391 = 100096 >= NN
#define BSLACK 13400  // mean 12500, sd ~112 -> ~8 sigma slack (input is fixed)
#define TILE 8192

typedef _Float16 h2 __attribute__((ext_vector_type(2)));
typedef _Float16 h4 __attribute__((ext_vector_type(4)));

__global__ void k_init(int* __restrict__ bcur) {
  int t = threadIdx.x;
  if (t < NBUK) bcur[t] = t * BSLACK;
}

// Pass A: LDS multisplit of one 8192-edge tile into 256 dst-buckets.
__global__ __launch_bounds__(1024) void k_bucket(const int* __restrict__ ei,
                                                 int* __restrict__ bcur,
                                                 long long* __restrict__ bpair) {
  __shared__ int hist[NBUK];
  __shared__ int bexc[NBUK];
  __shared__ int cnt[NBUK];
  __shared__ int gofs[NBUK];
  __shared__ long long sorted[TILE];  // 64 KB
  int t = threadIdx.x;
  const int* src = ei;
  const int* dst = ei + EE;
  int e0 = blockIdx.x * TILE;
  int tn = EE - e0;
  if (tn > TILE) tn = TILE;

  if (t < NBUK) { hist[t] = 0; cnt[t] = 0; }
  __syncthreads();

  for (int i = t; i < tn; i += 1024) {
    int d = __builtin_nontemporal_load(&dst[e0 + i]);
    atomicAdd(&hist[d / BRANGE], 1);
  }
  __syncthreads();

  int hv = 0;
  if (t < NBUK) { hv = hist[t]; bexc[t] = hv; }
  __syncthreads();
#pragma unroll
  for (int off = 1; off < NBUK; off <<= 1) {
    int x = 0;
    if (t < NBUK && t >= off) x = bexc[t - off];
    __syncthreads();
    if (t < NBUK) bexc[t] += x;
    __syncthreads();
  }
  if (t < NBUK) {
    int inc = bexc[t];
    bexc[t] = inc - hv;
    if (hv > 0) gofs[t] = atomicAdd(&bcur[t], hv);  // ~65K atomics total
  }
  __syncthreads();

  for (int i = t; i < tn; i += 1024) {
    int d = dst[e0 + i];
    int s = src[e0 + i];
    int q = d / BRANGE;
    int p = bexc[q] + atomicAdd(&cnt[q], 1);
    sorted[p] = ((long long)(unsigned)d << 32) | (unsigned)s;
  }
  __syncthreads();

  for (int i = t; i < tn; i += 1024) {
    long long pr = sorted[i];
    int q = (int)(unsigned)(pr >> 32) / BRANGE;
    __builtin_nontemporal_store(pr, &bpair[(size_t)gofs[q] + (i - bexc[q])]);
  }
}

// Fused CSR finalize: one 1024-thread block per bucket, zero global atomics.
__global__ __launch_bounds__(1024) void k_place(const long long* __restrict__ bpair,
                                                const int* __restrict__ bcur,
                                                float* __restrict__ dinv,
                                                int* __restrict__ row_ptr,
                                                int* __restrict__ col) {
  __shared__ int bs[NBUK];
  __shared__ int cnt[BRANGE];
  __shared__ int sc[1024];
  int b = blockIdx.x, t = threadIdx.x;

  if (t < NBUK) bs[t] = bcur[t] - t * BSLACK;
  __syncthreads();
#pragma unroll
  for (int off = 1; off < NBUK; off <<= 1) {
    int x = 0;
    if (t < NBUK && t >= off) x = bs[t - off];
    __syncthreads();
    if (t < NBUK) bs[t] += x;
    __syncthreads();
  }
  __syncthreads();
  int sz = bcur[b] - b * BSLACK;
  int colbase = bs[b] - sz;

  if (t < BRANGE) cnt[t] = 0;
  __syncthreads();

  int lo = b * BRANGE;
  int nnode = NN - lo;
  if (nnode > BRANGE) nnode = BRANGE;
  size_t e0 = (size_t)b * BSLACK;

  for (int i = t; i < sz; i += 1024) {
    long long pr = bpair[e0 + i];
    int d = (int)(unsigned)(pr >> 32);
    atomicAdd(&cnt[d - lo], 1);
  }
  __syncthreads();

  int v = (t < BRANGE) ? cnt[t] : 0;
  sc[t] = v;
  __syncthreads();
#pragma unroll
  for (int off = 1; off < 1024; off <<= 1) {
    int x = (t >= off) ? sc[t - off] : 0;
    __syncthreads();
    sc[t] += x;
    __syncthreads();
  }
  int excl = sc[t] - v;
  if (t < nnode) {
    row_ptr[lo + t] = colbase + excl;
    dinv[lo + t] = rsqrtf((float)(v + 1));  // +1 = self-loop
  }
  if (t < BRANGE) cnt[t] = colbase + excl;  // absolute cursor
  if (b == NBUK - 1 && t == 0) row_ptr[NN] = EE;
  __syncthreads();

  for (int i = t; i < sz; i += 1024) {
    long long pr = bpair[e0 + i];
    int d = (int)(unsigned)(pr >> 32);
    int s = (int)(unsigned)(pr & 0xffffffffLL);
    int pos = atomicAdd(&cnt[d - lo], 1);
    col[pos] = s;
  }
}

// G = dinv .* (X @ W), stored fp16 [node][32] (64B rows = 1 cache line).
template <int K>
__global__ __launch_bounds__(256) void k_gemm(const float* __restrict__ X,
                                              const float* __restrict__ W,
                                              const float* __restrict__ dinv,
                                              _Float16* __restrict__ Gout) {
  __shared__ float Wl[K * HID];
  __shared__ float xs[128 * 36];
  int t = threadIdx.x;
  for (int i = t; i < K * HID; i += 256) Wl[i] = W[i];
  int node0 = blockIdx.x * 128;
  int ng = t >> 3, f4 = t & 7;
  float acc[4][4];
#pragma unroll
  for (int j = 0; j < 4; j++)
#pragma unroll
    for (int c = 0; c < 4; c++) acc[j][c] = 0.f;

  for (int kc = 0; kc < K; kc += 32) {
    __syncthreads();
#pragma unroll
    for (int j = 0; j < 4; j++) {
      int idx = t + 256 * j;
      int r = idx >> 3, c4 = idx & 7;
      int row = node0 + r;
      if (row >= NN) row = NN - 1;
      float4 v = *reinterpret_cast<const float4*>(&X[(size_t)row * K + kc + c4 * 4]);
      *reinterpret_cast<float4*>(&xs[r * 36 + c4 * 4]) = v;
    }
    __syncthreads();
#pragma unroll
    for (int k4 = 0; k4 < 8; k4++) {
      float4 xv[4];
#pragma unroll
      for (int j = 0; j < 4; j++)
        xv[j] = *reinterpret_cast<const float4*>(&xs[(ng * 4 + j) * 36 + k4 * 4]);
#pragma unroll
      for (int kk = 0; kk < 4; kk++) {
        float4 wv = *reinterpret_cast<const float4*>(&Wl[(kc + k4 * 4 + kk) * HID + f4 * 4]);
#pragma unroll
        for (int j = 0; j < 4; j++) {
          float xvj = (kk == 0) ? xv[j].x : (kk == 1) ? xv[j].y : (kk == 2) ? xv[j].z : xv[j].w;
          acc[j][0] += xvj * wv.x;
          acc[j][1] += xvj * wv.y;
          acc[j][2] += xvj * wv.z;
          acc[j][3] += xvj * wv.w;
        }
      }
    }
  }
#pragma unroll
  for (int j = 0; j < 4; j++) {
    int node = node0 + ng * 4 + j;
    if (node < NN) {
      float s = dinv[node];
      h4 o;
      o.x = (_Float16)(acc[j][0] * s);
      o.y = (_Float16)(acc[j][1] * s);
      o.z = (_Float16)(acc[j][2] * s);
      o.w = (_Float16)(acc[j][3] * s);
      reinterpret_cast<h4*>(Gout)[(size_t)node * 8 + f4] = o;
    }
  }
}

// Fused agg + next-layer GEMM (layers 1-2). Per block: 16 nodes x 32 feats.
// A[n] = relu(dinv*sum G[src] + G[n]*?  ... standard agg) is completed
// in-block, round-trips through LDS, then G'[n] = dinv .* (A[n] @ Wn)
// (32x32 Wn in LDS) is written fp16 directly. No Abuf traffic.
__global__ __launch_bounds__(256) void k_aggmm(const _Float16* __restrict__ Gin,
                                               const int* __restrict__ col,
                                               const int* __restrict__ row_ptr,
                                               const float* __restrict__ dinv,
                                               const float* __restrict__ bias,
                                               const float* __restrict__ Wn,
                                               _Float16* __restrict__ Gout) {
  __shared__ float Wl[HID * HID];   // 4 KB next-layer weights
  __shared__ float As[16][HID + 1]; // padded A rows
  const h2* G2 = reinterpret_cast<const h2*>(Gin);
  int t = threadIdx.x;
  int h = t & 15;
  int slot = t >> 4;
  int n = blockIdx.x * 16 + slot;
#pragma unroll
  for (int i = 0; i < 4; i++) Wl[t + 256 * i] = Wn[t + 256 * i];
  int beg = row_ptr[n], end = row_ptr[n + 1];

  h2 g0 = G2[(size_t)n * 16 + h];  // self-loop term
  float ax0 = (float)g0.x, ay0 = (float)g0.y;
  float ax1 = 0.f, ay1 = 0.f, ax2 = 0.f, ay2 = 0.f, ax3 = 0.f, ay3 = 0.f;
  float ax4 = 0.f, ay4 = 0.f, ax5 = 0.f, ay5 = 0.f, ax6 = 0.f, ay6 = 0.f;
  float ax7 = 0.f, ay7 = 0.f;

  int i = beg;
  for (; i + 8 <= end; i += 8) {
    int s0 = __builtin_nontemporal_load(&col[i + 0]);
    int s1 = __builtin_nontemporal_load(&col[i + 1]);
    int s2 = __builtin_nontemporal_load(&col[i + 2]);
    int s3 = __builtin_nontemporal_load(&col[i + 3]);
    int s4 = __builtin_nontemporal_load(&col[i + 4]);
    int s5 = __builtin_nontemporal_load(&col[i + 5]);
    int s6 = __builtin_nontemporal_load(&col[i + 6]);
    int s7 = __builtin_nontemporal_load(&col[i + 7]);
    h2 v0 = G2[(size_t)s0 * 16 + h];
    h2 v1 = G2[(size_t)s1 * 16 + h];
    h2 v2 = G2[(size_t)s2 * 16 + h];
    h2 v3 = G2[(size_t)s3 * 16 + h];
    h2 v4 = G2[(size_t)s4 * 16 + h];
    h2 v5 = G2[(size_t)s5 * 16 + h];
    h2 v6 = G2[(size_t)s6 * 16 + h];
    h2 v7 = G2[(size_t)s7 * 16 + h];
    ax0 += (float)v0.x; ay0 += (float)v0.y;
    ax1 += (float)v1.x; ay1 += (float)v1.y;
    ax2 += (float)v2.x; ay2 += (float)v2.y;
    ax3 += (float)v3.x; ay3 += (float)v3.y;
    ax4 += (float)v4.x; ay4 += (float)v4.y;
    ax5 += (float)v5.x; ay5 += (float)v5.y;
    ax6 += (float)v6.x; ay6 += (float)v6.y;
    ax7 += (float)v7.x; ay7 += (float)v7.y;
  }
  for (; i < end; i++) {
    int s = __builtin_nontemporal_load(&col[i]);
    h2 v = G2[(size_t)s * 16 + h];
    ax0 += (float)v.x; ay0 += (float)v.y;
  }
  ax0 += ax1 + ax2 + ax3 + ax4 + ax5 + ax6 + ax7;
  ay0 += ay1 + ay2 + ay3 + ay4 + ay5 + ay6 + ay7;

  float s = dinv[n];
  float2 b = reinterpret_cast<const float2*>(bias)[h];
  float a0 = fmaxf(s * ax0 + b.x, 0.f);  // layers 1-2 always relu
  float a1 = fmaxf(s * ay0 + b.y, 0.f);
  As[slot][2 * h] = a0;
  As[slot][2 * h + 1] = a1;
  __syncthreads();

  // G'[n][2h,2h+1] = dinv[n] * sum_k A[n][k] * Wn[k][2h,2h+1]
  float o0 = 0.f, o1 = 0.f;
#pragma unroll
  for (int k = 0; k < HID; k++) {
    float a = As[slot][k];  // broadcast across the 16 h-lanes
    o0 += a * Wl[k * HID + 2 * h];
    o1 += a * Wl[k * HID + 2 * h + 1];
  }
  h2 o;
  o.x = (_Float16)(o0 * s);
  o.y = (_Float16)(o1 * s);
  reinterpret_cast<h2*>(Gout)[(size_t)n * 16 + h] = o;
}

// Final-layer agg (no relu, fp32 out for pool). Same gather structure.
__global__ __launch_bounds__(256) void k_agg(const _Float16* __restrict__ Gin,
                                             const int* __restrict__ col,
                                             const int* __restrict__ row_ptr,
                                             const float* __restrict__ dinv,
                                             const float* __restrict__ bias,
                                             float* __restrict__ Xout) {
  const h2* G2 = reinterpret_cast<const h2*>(Gin);
  int t = threadIdx.x;
  int h = t & 15;
  int slot = t >> 4;
  int n = blockIdx.x * 16 + slot;
  int beg = row_ptr[n], end = row_ptr[n + 1];

  h2 g0 = G2[(size_t)n * 16 + h];  // self-loop term
  float ax0 = (float)g0.x, ay0 = (float)g0.y;
  float ax1 = 0.f, ay1 = 0.f, ax2 = 0.f, ay2 = 0.f, ax3 = 0.f, ay3 = 0.f;
  float ax4 = 0.f, ay4 = 0.f, ax5 = 0.f, ay5 = 0.f, ax6 = 0.f, ay6 = 0.f;
  float ax7 = 0.f, ay7 = 0.f;

  int i = beg;
  for (; i + 8 <= end; i += 8) {
    int s0 = __builtin_nontemporal_load(&col[i + 0]);
    int s1 = __builtin_nontemporal_load(&col[i + 1]);
    int s2 = __builtin_nontemporal_load(&col[i + 2]);
    int s3 = __builtin_nontemporal_load(&col[i + 3]);
    int s4 = __builtin_nontemporal_load(&col[i + 4]);
    int s5 = __builtin_nontemporal_load(&col[i + 5]);
    int s6 = __builtin_nontemporal_load(&col[i + 6]);
    int s7 = __builtin_nontemporal_load(&col[i + 7]);
    h2 v0 = G2[(size_t)s0 * 16 + h];
    h2 v1 = G2[(size_t)s1 * 16 + h];
    h2 v2 = G2[(size_t)s2 * 16 + h];
    h2 v3 = G2[(size_t)s3 * 16 + h];
    h2 v4 = G2[(size_t)s4 * 16 + h];
    h2 v5 = G2[(size_t)s5 * 16 + h];
    h2 v6 = G2[(size_t)s6 * 16 + h];
    h2 v7 = G2[(size_t)s7 * 16 + h];
    ax0 += (float)v0.x; ay0 += (float)v0.y;
    ax1 += (float)v1.x; ay1 += (float)v1.y;
    ax2 += (float)v2.x; ay2 += (float)v2.y;
    ax3 += (float)v3.x; ay3 += (float)v3.y;
    ax4 += (float)v4.x; ay4 += (float)v4.y;
    ax5 += (float)v5.x; ay5 += (float)v5.y;
    ax6 += (float)v6.x; ay6 += (float)v6.y;
    ax7 += (float)v7.x; ay7 += (float)v7.y;
  }
  for (; i < end; i++) {
    int s = __builtin_nontemporal_load(&col[i]);
    h2 v = G2[(size_t)s * 16 + h];
    ax0 += (float)v.x; ay0 += (float)v.y;
  }
  ax0 += ax1 + ax2 + ax3 + ax4 + ax5 + ax6 + ax7;
  ay0 += ay1 + ay2 + ay3 + ay4 + ay5 + ay6 + ay7;

  float s = dinv[n];
  float2 b = reinterpret_cast<const float2*>(bias)[h];
  float2 v;
  v.x = s * ax0 + b.x;
  v.y = s * ay0 + b.y;
  reinterpret_cast<float2*>(Xout)[(size_t)n * 16 + h] = v;
}

// Mean-pool: batch is sorted, so flush-on-graph-change keeps atomics rare.
__global__ __launch_bounds__(256) void k_pool(const float* __restrict__ X,
                                              const int* __restrict__ batch,
                                              float* __restrict__ sums,
                                              int* __restrict__ counts) {
  int t = threadIdx.x;
  int f = t & 31, slot = t >> 5;
  int base = blockIdx.x * 512;
  float acc = 0.f;
  int cnt = 0, cur = -1;
  for (int i = 0; i < 64; i++) {
    int n = base + slot + i * 8;
    if (n >= NN) break;
    int g = batch[n];
    if (g != cur) {
      if (cur >= 0) {
        atomicAdd(&sums[cur * HID + f], acc);
        if (f == 0) atomicAdd(&counts[cur], cnt);
      }
      cur = g;
      acc = 0.f;
      cnt = 0;
    }
    acc += X[(size_t)n * HID + f];
    cnt++;
  }
  if (cur >= 0) {
    atomicAdd(&sums[cur * HID + f], acc);
    if (f == 0) atomicAdd(&counts[cur], cnt);
  }
}

__global__ void k_fc(const float* __restrict__ sums, const int* __restrict__ counts,
                     const float* __restrict__ Wfc, const float* __restrict__ bfc,
                     float* __restrict__ out) {
  int idx = blockIdx.x * 256 + threadIdx.x;
  if (idx >= NGR * NC) return;
  int g = idx / NC, c = idx % NC;
  float inv = 1.f / fmaxf((float)counts[g], 1.f);
  float acc = bfc[c];
#pragma unroll
  for (int k = 0; k < HID; k++) acc += sums[g * HID + k] * inv * Wfc[k * NC + c];
  out[idx] = acc;
}

extern "C" void kernel_launch(void* const* d_in, const int* in_sizes, int n_in,
                              void* d_out, int out_size, void* d_ws, size_t ws_size,
                              hipStream_t stream) {
  (void)in_sizes; (void)n_in; (void)out_size; (void)ws_size;
  const float* x = (const float*)d_in[0];
  const int* ei = (const int*)d_in[1];
  const int* batch = (const int*)d_in[2];
  const float* W1 = (const float*)d_in[3];
  const float* b1 = (const float*)d_in[4];
  const float* W2 = (const float*)d_in[5];
  const float* b2 = (const float*)d_in[6];
  const float* W3 = (const float*)d_in[7];
  const float* b3 = (const float*)d_in[8];
  const float* Wfc = (const float*)d_in[9];
  const float* bfc = (const float*)d_in[10];
  float* out = (float*)d_out;

  char* ws = (char*)d_ws;
  size_t off = 0;
  auto alloc = [&](size_t bytes) -> void* {
    void* p = ws + off;
    off = (off + bytes + 255) & ~(size_t)255;
    return p;
  };
  float* dinv = (float*)alloc((size_t)NN * 4);
  int* row_ptr = (int*)alloc((size_t)(NN + 1) * 4);
  int* bcur = (int*)alloc(NBUK * 4);
  int* col = (int*)alloc((size_t)EE * 4);
  // Union region: bpair (CSR build only) overlaps G1/G2/Abuf (layer phase).
  size_t bpair_bytes = (size_t)NBUK * BSLACK * 8;          // 27.4 MB
  size_t gbuf_bytes = (size_t)NN * HID * 2;                // 6.4 MB (fp16)
  size_t abuf_bytes = (size_t)NN * HID * 4;                // 12.8 MB (fp32)
  size_t need = 2 * gbuf_bytes + abuf_bytes;               // G1 + G2 + Abuf
  char* uni = (char*)alloc(bpair_bytes > need ? bpair_bytes : need);
  long long* bpair = (long long*)uni;
  _Float16* G1 = (_Float16*)uni;
  _Float16* G2b = (_Float16*)(uni + gbuf_bytes);
  float* Abuf = (float*)(uni + 2 * gbuf_bytes);
  float* sums = (float*)alloc((size_t)NGR * HID * 4);
  int* counts = (int*)alloc((size_t)NGR * 4);

  hipMemsetAsync(sums, 0, (size_t)NGR * HID * 4, stream);
  hipMemsetAsync(counts, 0, (size_t)NGR * 4, stream);

  k_init<<<1, NBUK, 0, stream>>>(bcur);
  k_bucket<<<(EE + TILE - 1) / TILE, 1024, 0, stream>>>(ei, bcur, bpair);
  k_place<<<NBUK, 1024, 0, stream>>>(bpair, bcur, dinv, row_ptr, col);

  k_gemm<FIN><<<(NN + 127) / 128, 256, 0, stream>>>(x, W1, dinv, G1);
  // Fused: A1 = relu(agg(G1)+b1); G2 = dinv.*(A1@W2)
  k_aggmm<<<NN / 16, 256, 0, stream>>>(G1, col, row_ptr, dinv, b1, W2, G2b);
  // Fused: A2 = relu(agg(G2)+b2); G3 = dinv.*(A2@W3)  (reuse G1 buffer)
  k_aggmm<<<NN / 16, 256, 0, stream>>>(G2b, col, row_ptr, dinv, b2, W3, G1);
  // Final: A3 = agg(G3)+b3 (no relu), fp32 for pool
  k_agg<<<NN / 16, 256, 0, stream>>>(G1, col, row_ptr, dinv, b3, Abuf);

  k_pool<<<(NN + 511) / 512, 256, 0, stream>>>(Abuf, batch, sums, counts);
  k_fc<<<(NGR * NC + 255) / 256, 256, 0, stream>>>(sums, counts, Wfc, bfc, out);
}